// Round 6
// baseline (621.315 us; speedup 1.0000x reference)
//
#include <hip/hip_runtime.h>

#define N_NODES 100000
#define DIM 128
#define N_REL 8
#define N_EDGES 625000
#define NG 6252              // dst 16-groups incl. pad (3126 blocks * 2)
#define NBINS (N_REL * NG)   // 50016 (rel, dst16-group) bins
#define BINCAP 96            // lambda = 12.5 edges/bin; P(>96) ~ 1e-40
#define N_PADROWS 100032

// fp32 -> bf16, round-to-nearest-even (used for Wt only)
__device__ __forceinline__ unsigned short f2bf(float f) {
    unsigned int u = __float_as_uint(f);
    u += 0x7fffu + ((u >> 16) & 1u);
    return (unsigned short)(u >> 16);
}

// prep: W -> MFMA B-frag order + ONE-PASS edge binning into fixed-capacity bins.
// Bins are (rel, dst>>4): fused accumulates orderlessly (LDS fp32 atomics), so no
// exact-key sort is needed -> scan_kernel and fill_kernel are gone entirely.
__global__ __launch_bounds__(256) void prep_kernel(const float* __restrict__ relw,
                                                   const float* __restrict__ selfw,
                                                   const int* __restrict__ src,
                                                   const int* __restrict__ dst,
                                                   const int* __restrict__ rel,
                                                   unsigned short* __restrict__ Wt,
                                                   int* __restrict__ cnt,
                                                   unsigned int* __restrict__ ebuf) {
    int i = blockIdx.x * 256 + threadIdx.x;      // grid covers N_EDGES
    if (i < 147456) {  // Wt[(((r*4+ks)*8+t)*64+lane)*8+j] = W_r[din=ks*32+quad*8+j][dout=t*16+m16]
        int j = i & 7;
        int lane = (i >> 3) & 63;
        int t = (i >> 9) & 7;
        int ks = (i >> 12) & 3;
        int r = i >> 14;
        int m16 = lane & 15, quad = lane >> 4;
        int din = ks * 32 + quad * 8 + j;
        int dout = t * 16 + m16;
        float v = (r < 8) ? relw[(r << 14) + (din << 7) + dout] : selfw[(din << 7) + dout];
        Wt[i] = f2bf(v);
    }
    if (i < N_EDGES) {
        int d = dst[i];
        int bin = rel[i] * NG + (d >> 4);
        int pos = atomicAdd(&cnt[bin], 1);
        if (pos < BINCAP)
            ebuf[bin * BINCAP + pos] = (unsigned int)src[i] | ((unsigned int)(d & 15) << 17);
    }
}

typedef __attribute__((ext_vector_type(8))) short frag8;
typedef __attribute__((ext_vector_type(4))) float f32x4;

// 2x f32 -> packed bf16 (RNE); frag8 channel j = float j
__device__ __forceinline__ frag8 pack8(float4 a, float4 b) {
    union { frag8 f; unsigned int u[4]; } r;
    asm("v_cvt_pk_bf16_f32 %0, %1, %2" : "=v"(r.u[0]) : "v"(a.x), "v"(a.y));
    asm("v_cvt_pk_bf16_f32 %0, %1, %2" : "=v"(r.u[1]) : "v"(a.z), "v"(a.w));
    asm("v_cvt_pk_bf16_f32 %0, %1, %2" : "=v"(r.u[2]) : "v"(b.x), "v"(b.y));
    asm("v_cvt_pk_bf16_f32 %0, %1, %2" : "=v"(r.u[3]) : "v"(b.z), "v"(b.w));
    return r.f;
}

// Fused aggregate+transform, ORDERLESS accumulation:
//  block = 32 dst rows, 4 waves: g=wave>>1 row-group (16 rows), h=wave&1 rel-group
//  (relations h*4..h*4+3; h=0 also does selfloop). Merge via LDS (2 barriers).
//  Per relation: wave reads its bin (lambda=12.5 edges), each edge: 2 global loads
//  (lane=channel c and c+64 of the fp32 source row) + 2 ds_add_f32 into an fp32
//  16x128 LDS tile (XOR-swizzled rows). NO run-detection chain, NO ordering needed.
//  Degrees from a 16-slot LDS float histogram (1 shared atomic per edge).
//  Frag build: tile row m16 scaled by 1/deg, cvt_pk -> bf16 frag -> MFMA.
//  Tile swizzle: float index = row*128 + (c ^ ((row&7)<<2)):
//   - accumulate (same row, c=lane / lane+64): banks lane%32 -> 2-way = free
//   - frag read float4 (rows vary): granule (quad*2+hh)^(m16&7) -> 2/granule = free
__global__ __launch_bounds__(256, 4) void fused_kernel(const float* __restrict__ x,
                                                       const unsigned short* __restrict__ Wt,
                                                       const int* __restrict__ cnt,
                                                       const unsigned int* __restrict__ ebuf,
                                                       const float* __restrict__ bias,
                                                       float* __restrict__ out) {
    __shared__ __align__(16) float lds[4][2112];   // per wave: 2048 tile + 16 scnt + pad

    const int tid = threadIdx.x;
    const int wave = tid >> 6, lane = tid & 63;
    const int g = wave >> 1, h = wave & 1;
    const int m16 = lane & 15, quad = lane >> 4;
    const int dbase = blockIdx.x * 32 + g * 16;
    const int grp = blockIdx.x * 2 + g;
    float* tile = lds[wave];
    float* scnt = lds[wave] + 2048;
    const int r0 = h * 4;

    // prefetch all 4 bins' counts + first-64 edge words (independent, one latency)
    int clA = cnt[(r0 + 0) * NG + grp];
    int clB = cnt[(r0 + 1) * NG + grp];
    int clC = cnt[(r0 + 2) * NG + grp];
    int clD = cnt[(r0 + 3) * NG + grp];
    unsigned int ewA = ebuf[((r0 + 0) * NG + grp) * BINCAP + lane];
    unsigned int ewB = ebuf[((r0 + 1) * NG + grp) * BINCAP + lane];
    unsigned int ewC = ebuf[((r0 + 2) * NG + grp) * BINCAP + lane];
    unsigned int ewD = ebuf[((r0 + 3) * NG + grp) * BINCAP + lane];
    if (clA > BINCAP) clA = BINCAP;
    if (clB > BINCAP) clB = BINCAP;
    if (clC > BINCAP) clC = BINCAP;
    if (clD > BINCAP) clD = BINCAP;

    f32x4 acc[8];
#pragma unroll
    for (int t = 0; t < 8; t++) acc[t] = (f32x4){0.f, 0.f, 0.f, 0.f};

    if (h == 0) {
        // ---- selfloop: A-frags straight from fp32 x (clamped pad rows; their
        // output rows are never stored) -- hides the ebuf prefetch latency ----
        int srow = dbase + m16;
        if (srow >= N_NODES) srow = N_NODES - 1;
        const float* ap = x + (size_t)srow * DIM;
#pragma unroll
        for (int ks = 0; ks < 4; ks++) {
            float4 a0 = *(const float4*)(ap + ks * 32 + quad * 8);
            float4 a1 = *(const float4*)(ap + ks * 32 + quad * 8 + 4);
            frag8 a = pack8(a0, a1);
            const frag8* bp = (const frag8*)Wt + ((8 * 4 + ks) * 8) * 64 + lane;
#pragma unroll
            for (int t = 0; t < 8; t++)
                acc[t] = __builtin_amdgcn_mfma_f32_16x16x32_bf16(a, bp[t * 64], acc[t], 0, 0, 0);
        }
    }

#pragma unroll 1
    for (int r = 0; r < 4; r++) {
        // zero tile + degree counters (prev rel's frag reads are wave-ordered before this)
        {
            float4 z = {0.f, 0.f, 0.f, 0.f};
#pragma unroll
            for (int j = 0; j < 8; j++)
                *(float4*)(tile + j * 256 + lane * 4) = z;
            if (lane < 16) scnt[lane] = 0.0f;
        }

        int cl = clA;
        unsigned int ew = ewA;
        int binbase = ((r0 + r) * NG + grp) * BINCAP;

#pragma unroll 1
        for (int b0 = 0; b0 < cl; b0 += 64) {
            int ccl = cl - b0; if (ccl > 64) ccl = 64;
            if (b0 > 0) ew = ebuf[binbase + b0 + lane];   // astronomically rare
            // per-edge degree count (lane owns its own edge word)
            if (b0 + lane < cl) atomicAdd(&scnt[(ew >> 17) & 15u], 1.0f);
#pragma unroll 1
            for (int i = 0; i < ccl; i += 16) {
                float wlo[16], whi[16];
                int dlv[16];
#pragma unroll
                for (int k = 0; k < 16; k++) {           // issue up to 32 independent loads
                    if (i + k < ccl) {                   // wave-uniform guard
                        unsigned int u = (unsigned)__builtin_amdgcn_readlane((int)ew, i + k);
                        dlv[k] = (int)((u >> 17) & 15u);
                        const float* rp = x + (size_t)(u & 0x1ffffu) * DIM;
                        wlo[k] = rp[lane];
                        whi[k] = rp[64 + lane];
                    }
                }
#pragma unroll
                for (int k = 0; k < 16; k++) {           // orderless fp32 LDS accumulate
                    if (i + k < ccl) {
                        int s = (dlv[k] & 7) << 2;
                        atomicAdd(&tile[dlv[k] * 128 + (lane ^ s)], wlo[k]);
                        atomicAdd(&tile[dlv[k] * 128 + ((64 + lane) ^ s)], whi[k]);
                    }
                }
            }
        }

        // frag build: mean = tile/deg, cvt to bf16, MFMA (LDS in-order per wave)
        {
            float scv = scnt[m16];
            float inv = __builtin_amdgcn_rcpf(scv > 1.0f ? scv : 1.0f);
            int s = (m16 & 7) << 2;
#pragma unroll
            for (int ks = 0; ks < 4; ks++) {
                int c0 = ks * 32 + quad * 8;
                float4 f0 = *(const float4*)(tile + m16 * 128 + (c0 ^ s));
                float4 f1 = *(const float4*)(tile + m16 * 128 + ((c0 + 4) ^ s));
                f0.x *= inv; f0.y *= inv; f0.z *= inv; f0.w *= inv;
                f1.x *= inv; f1.y *= inv; f1.z *= inv; f1.w *= inv;
                frag8 a = pack8(f0, f1);
                const frag8* bp = (const frag8*)Wt + (((r0 + r) * 4 + ks) * 8) * 64 + lane;
#pragma unroll
                for (int t = 0; t < 8; t++)
                    acc[t] = __builtin_amdgcn_mfma_f32_16x16x32_bf16(a, bp[t * 64], acc[t], 0, 0, 0);
            }
        }

        // rotate relation state (scalars only)
        clA = clB; clB = clC; clC = clD;
        ewA = ewB; ewB = ewC; ewC = ewD;
    }

    // ---- merge rel-halves: h=1 waves publish acc via LDS (reusing wave-pair tiles) ----
    __syncthreads();
    float* mbuf = lds[g * 2];
    if (h == 1) {
#pragma unroll
        for (int t = 0; t < 8; t++)
            *(f32x4*)(mbuf + (t * 64 + lane) * 4) = acc[t];
    }
    __syncthreads();
    if (h == 0) {
#pragma unroll
        for (int t = 0; t < 8; t++) {
            f32x4 m = *(f32x4*)(mbuf + (t * 64 + lane) * 4);
            acc[t] += m;
        }

        // ---- epilogue: +bias, two column-halves through mbuf (wave-private now) ----
        float* S = mbuf;
#pragma unroll
        for (int hh = 0; hh < 2; hh++) {
#pragma unroll
            for (int tt = 0; tt < 4; tt++) {
                int t = hh * 4 + tt;
                float bc = bias[t * 16 + m16];
#pragma unroll
                for (int i = 0; i < 4; i++)
                    S[(quad * 4 + i) * 68 + tt * 16 + m16] = acc[t][i] + bc;
            }
#pragma unroll
            for (int c = 0; c < 4; c++) {
                int row16 = c * 4 + quad;
                int gr = dbase + row16;
                if (gr < N_NODES)
                    *(float4*)(out + (size_t)gr * DIM + hh * 64 + m16 * 4) =
                        *(float4*)(S + row16 * 68 + m16 * 4);
            }
        }
    }
}

extern "C" void kernel_launch(void* const* d_in, const int* in_sizes, int n_in,
                              void* d_out, int out_size, void* d_ws, size_t ws_size,
                              hipStream_t stream) {
    const float* x = (const float*)d_in[0];
    const int* edge_index = (const int*)d_in[1]; // [2][E]: src then dst
    const int* edge_type = (const int*)d_in[2];
    const float* relw = (const float*)d_in[3];
    const float* selfw = (const float*)d_in[4];
    const float* bias = (const float*)d_in[5];
    float* out = (float*)d_out;
    (void)in_sizes; (void)n_in; (void)out_size; (void)ws_size;

    // ws: Wt 0.29MB | cnt 0.2MB | ebuf 19.2MB   (~19.7MB total)
    char* ws = (char*)d_ws;
    size_t off = 0;
    unsigned short* Wt = (unsigned short*)(ws + off); off += (size_t)9 * DIM * DIM * 2;
    int* cnt = (int*)(ws + off); off += (size_t)NBINS * 4;
    unsigned int* ebuf = (unsigned int*)(ws + off); off += (size_t)NBINS * BINCAP * 4;

    const int* src = edge_index;
    const int* dst = edge_index + N_EDGES;

    hipMemsetAsync(cnt, 0, (size_t)NBINS * 4, stream);
    prep_kernel<<<(N_EDGES + 255) / 256, 256, 0, stream>>>(relw, selfw, src, dst, edge_type,
                                                           Wt, cnt, ebuf);
    fused_kernel<<<N_PADROWS / 32, 256, 0, stream>>>(x, Wt, cnt, ebuf, bias, out);
}

// Round 7
// 331.289 us; speedup vs baseline: 1.8754x; 1.8754x over previous
//
#include <hip/hip_runtime.h>

#define N_NODES 100000
#define DIM 128
#define N_REL 8
#define N_EDGES 625000
#define NG 6252              // dst 16-groups incl. pad (3126 blocks * 2)
#define NBINS (N_REL * NG)   // 50016 (rel, dst16-group) bins
#define BINCAP 64            // lambda = 12.5; fixed-seed max bin ~35 << 64
#define N_PADROWS 100032

// fp32 -> bf16, round-to-nearest-even
__device__ __forceinline__ unsigned short f2bf(float f) {
    unsigned int u = __float_as_uint(f);
    u += 0x7fffu + ((u >> 16) & 1u);
    return (unsigned short)(u >> 16);
}

// packed 2x f32 -> bf16x2 (hw round)
__device__ __forceinline__ unsigned int pkbf(float a, float b) {
    unsigned int r;
    asm("v_cvt_pk_bf16_f32 %0, %1, %2" : "=v"(r) : "v"(a), "v"(b));
    return r;
}

// prep (ONE pass): x->bf16 (12.8M elems, 4/thread), zero xb pad rows, W -> MFMA
// B-frag order, and bin every edge by (rel, dst>>4). Bin contents are UNORDERED
// (fused accumulates per-dst in registers), so scan/fill/rank kernels are gone.
__global__ __launch_bounds__(256) void prep_kernel(const float* __restrict__ x,
                                                   const float* __restrict__ relw,
                                                   const float* __restrict__ selfw,
                                                   const int* __restrict__ src,
                                                   const int* __restrict__ dst,
                                                   const int* __restrict__ rel,
                                                   unsigned short* __restrict__ xb,
                                                   unsigned short* __restrict__ Wt,
                                                   int* __restrict__ cnt,
                                                   unsigned int* __restrict__ ebuf) {
    int i = blockIdx.x * 256 + threadIdx.x;      // 0 .. 3,199,999 exact
    {
        float4 v = *(const float4*)(x + (size_t)i * 4);
        unsigned short t[4] = {f2bf(v.x), f2bf(v.y), f2bf(v.z), f2bf(v.w)};
        *(uint2*)(xb + (size_t)i * 4) = *(const uint2*)t;
    }
    if (i < 512) {  // zero pad rows 100000..100031
        uint4 z = {0, 0, 0, 0};
        *(uint4*)(xb + (size_t)N_NODES * DIM + i * 8) = z;
    }
    if (i < 147456) {  // Wt[(((r*4+ks)*8+t)*64+lane)*8+j] = W_r[din=ks*32+quad*8+j][dout=t*16+m16]
        int j = i & 7;
        int lane = (i >> 3) & 63;
        int t = (i >> 9) & 7;
        int ks = (i >> 12) & 3;
        int r = i >> 14;
        int m16 = lane & 15, quad = lane >> 4;
        int din = ks * 32 + quad * 8 + j;
        int dout = t * 16 + m16;
        float v = (r < 8) ? relw[(r << 14) + (din << 7) + dout] : selfw[(din << 7) + dout];
        Wt[i] = f2bf(v);
    }
    if (i < N_EDGES) {
        int d = dst[i];
        int bin = rel[i] * NG + (d >> 4);
        int pos = atomicAdd(&cnt[bin], 1);
        if (pos < BINCAP)
            ebuf[bin * BINCAP + pos] = (unsigned int)src[i] | ((unsigned int)(d & 15) << 17);
    }
}

typedef __attribute__((ext_vector_type(8))) short frag8;
typedef __attribute__((ext_vector_type(4))) float f32x4;

// Fused aggregate+transform, register scatter-accumulate:
//  block = 32 dst rows, 4 waves: g=wave>>1 row-group (16 rows), h=wave&1 rel-group
//  (relations h*4..h*4+3; h=0 also does selfloop). Merge via LDS (2 barriers).
//  Per relation the wave reads its bin (<=64 edges, one ew load): each edge is
//  one u32 load/lane (2 bf16 channels of the src row) and a register accumulate
//  rx[dl]/ry[dl] -- dl comes from readlane => SGPR => the 16-case switch is a
//  scalar branch tree (~6 SALU/edge) and rx/ry indices are all static (no scratch).
//  NO LDS atomics (round-6's 4.5x regression), NO ordered ebuf, NO tile pre-zero.
//  Degrees via 16 ballots/bin. Means -> swizzled LDS tile (round-3 layout) -> MFMA.
__global__ __launch_bounds__(256, 4) void fused_kernel(const unsigned short* __restrict__ xb,
                                                       const unsigned short* __restrict__ Wt,
                                                       const int* __restrict__ cnt,
                                                       const unsigned int* __restrict__ ebuf,
                                                       const float* __restrict__ bias,
                                                       float* __restrict__ out) {
    __shared__ __align__(16) unsigned char ldsraw[4 * 4096];   // 16 KB

    const int tid = threadIdx.x;
    const int wave = tid >> 6, lane = tid & 63;
    const int g = wave >> 1, h = wave & 1;
    const int m16 = lane & 15, quad = lane >> 4;
    const int dbase = blockIdx.x * 32 + g * 16;
    const int grp = blockIdx.x * 2 + g;
    unsigned char* slab = ldsraw + wave * 4096;
    const unsigned int* xb32 = (const unsigned int*)xb;
    const int r0 = h * 4;

    // prefetch all 4 bins' counts + edge words up-front (independent, one latency)
    int clA = cnt[(r0 + 0) * NG + grp];
    int clB = cnt[(r0 + 1) * NG + grp];
    int clC = cnt[(r0 + 2) * NG + grp];
    int clD = cnt[(r0 + 3) * NG + grp];
    unsigned int ewA = ebuf[((r0 + 0) * NG + grp) * BINCAP + lane];
    unsigned int ewB = ebuf[((r0 + 1) * NG + grp) * BINCAP + lane];
    unsigned int ewC = ebuf[((r0 + 2) * NG + grp) * BINCAP + lane];
    unsigned int ewD = ebuf[((r0 + 3) * NG + grp) * BINCAP + lane];
    if (clA > BINCAP) clA = BINCAP;
    if (clB > BINCAP) clB = BINCAP;
    if (clC > BINCAP) clC = BINCAP;
    if (clD > BINCAP) clD = BINCAP;

    f32x4 acc[8];
#pragma unroll
    for (int t = 0; t < 8; t++) acc[t] = (f32x4){0.f, 0.f, 0.f, 0.f};

    if (h == 0) {
        // ---- selfloop: A-frags direct from xb (pad rows zeroed); hides ew latency ----
        const unsigned short* ap = xb + (size_t)(dbase + m16) * DIM;
#pragma unroll
        for (int ks = 0; ks < 4; ks++) {
            frag8 a = *(const frag8*)(ap + ks * 32 + quad * 8);
            const frag8* bp = (const frag8*)Wt + ((8 * 4 + ks) * 8) * 64 + lane;
#pragma unroll
            for (int t = 0; t < 8; t++)
                acc[t] = __builtin_amdgcn_mfma_f32_16x16x32_bf16(a, bp[t * 64], acc[t], 0, 0, 0);
        }
    }

#pragma unroll 1
    for (int r = 0; r < 4; r++) {
        int cl = clA;
        unsigned int ew = ewA;

        if (cl > 0) {       // wave-uniform; empty bin contributes nothing
            float rx[16], ry[16];
#pragma unroll
            for (int j = 0; j < 16; j++) { rx[j] = 0.f; ry[j] = 0.f; }

#pragma unroll 1
            for (int i0 = 0; i0 < cl; i0 += 8) {
                int kk = cl - i0; if (kk > 8) kk = 8;
                int uu[8];
                unsigned int vv[8];
#pragma unroll
                for (int k = 0; k < 8; k++) {    // branchless clamped loads, 8-deep MLP
                    int li = i0 + k; if (li >= cl) li = cl - 1;
                    uu[k] = __builtin_amdgcn_readlane((int)ew, li);
                    vv[k] = xb32[(size_t)((unsigned)uu[k] & 0x1ffffu) * 64 + lane];
                }
#pragma unroll
                for (int k = 0; k < 8; k++) {
                    if (k < kk) {                // wave-uniform guard
                        int dl = (int)(((unsigned)uu[k] >> 17) & 15u);
                        float fx = __uint_as_float(vv[k] << 16);
                        float fy = __uint_as_float(vv[k] & 0xffff0000u);
                        switch (dl) {            // dl is SGPR -> scalar branch tree
                            case 0:  rx[0]  += fx; ry[0]  += fy; break;
                            case 1:  rx[1]  += fx; ry[1]  += fy; break;
                            case 2:  rx[2]  += fx; ry[2]  += fy; break;
                            case 3:  rx[3]  += fx; ry[3]  += fy; break;
                            case 4:  rx[4]  += fx; ry[4]  += fy; break;
                            case 5:  rx[5]  += fx; ry[5]  += fy; break;
                            case 6:  rx[6]  += fx; ry[6]  += fy; break;
                            case 7:  rx[7]  += fx; ry[7]  += fy; break;
                            case 8:  rx[8]  += fx; ry[8]  += fy; break;
                            case 9:  rx[9]  += fx; ry[9]  += fy; break;
                            case 10: rx[10] += fx; ry[10] += fy; break;
                            case 11: rx[11] += fx; ry[11] += fy; break;
                            case 12: rx[12] += fx; ry[12] += fy; break;
                            case 13: rx[13] += fx; ry[13] += fy; break;
                            case 14: rx[14] += fx; ry[14] += fy; break;
                            default: rx[15] += fx; ry[15] += fy; break;
                        }
                    }
                }
            }

            // degrees from ballots + mean write to swizzled tile (round-3 layout)
            int mydl = (int)((ew >> 17) & 15u);
            bool act = lane < cl;
#pragma unroll
            for (int j = 0; j < 16; j++) {
                int dg = (int)__popcll(__ballot(act && (mydl == j)));
                float inv = __builtin_amdgcn_rcpf(dg > 0 ? (float)dg : 1.0f);
                unsigned int p = pkbf(rx[j] * inv, ry[j] * inv);
                int bb = (lane >> 2) ^ j;
                *(unsigned int*)(slab + j * 256 + bb * 16 + (lane & 3) * 4) = p;
            }

            // A-frags from swizzled tile + MFMA (LDS in-order per wave; no barrier)
#pragma unroll
            for (int ks = 0; ks < 4; ks++) {
                int bb = (4 * ks + quad) ^ m16;
                frag8 a = *(const frag8*)(slab + m16 * 256 + bb * 16);
                const frag8* bp = (const frag8*)Wt + (((r0 + r) * 4 + ks) * 8) * 64 + lane;
#pragma unroll
                for (int t = 0; t < 8; t++)
                    acc[t] = __builtin_amdgcn_mfma_f32_16x16x32_bf16(a, bp[t * 64], acc[t], 0, 0, 0);
            }
        }

        // rotate relation state (scalars only)
        clA = clB; clB = clC; clC = clD;
        ewA = ewB; ewB = ewC; ewC = ewD;
    }

    // ---- merge rel-halves: h=1 waves publish acc via LDS (reusing wave-pair slabs) ----
    __syncthreads();
    unsigned char* mbuf = ldsraw + g * 8192;
    if (h == 1) {
#pragma unroll
        for (int t = 0; t < 8; t++)
            *(f32x4*)(mbuf + (t * 64 + lane) * 16) = acc[t];
    }
    __syncthreads();
    if (h == 0) {
#pragma unroll
        for (int t = 0; t < 8; t++) {
            f32x4 m = *(f32x4*)(mbuf + (t * 64 + lane) * 16);
            acc[t] += m;
        }

        // ---- epilogue: +bias, two column-halves through mbuf (wave-private now;
        // own reads above are LDS-ordered before these writes)
        float* S = (float*)mbuf;
#pragma unroll
        for (int hh = 0; hh < 2; hh++) {
#pragma unroll
            for (int tt = 0; tt < 4; tt++) {
                int t = hh * 4 + tt;
                float bc = bias[t * 16 + m16];
#pragma unroll
                for (int i = 0; i < 4; i++)
                    S[(quad * 4 + i) * 68 + tt * 16 + m16] = acc[t][i] + bc;
            }
#pragma unroll
            for (int c = 0; c < 4; c++) {
                int row16 = c * 4 + quad;
                int gr = dbase + row16;
                if (gr < N_NODES)
                    *(float4*)(out + (size_t)gr * DIM + hh * 64 + m16 * 4) =
                        *(float4*)(S + row16 * 68 + m16 * 4);
            }
        }
    }
}

extern "C" void kernel_launch(void* const* d_in, const int* in_sizes, int n_in,
                              void* d_out, int out_size, void* d_ws, size_t ws_size,
                              hipStream_t stream) {
    const float* x = (const float*)d_in[0];
    const int* edge_index = (const int*)d_in[1]; // [2][E]: src then dst
    const int* edge_type = (const int*)d_in[2];
    const float* relw = (const float*)d_in[3];
    const float* selfw = (const float*)d_in[4];
    const float* bias = (const float*)d_in[5];
    float* out = (float*)d_out;
    (void)in_sizes; (void)n_in; (void)out_size; (void)ws_size;

    // ws: xb 25.6MB | Wt 0.29MB | cnt 0.2MB | ebuf 12.8MB  (~38.9MB total)
    char* ws = (char*)d_ws;
    size_t off = 0;
    unsigned short* xb = (unsigned short*)(ws + off); off += (size_t)N_PADROWS * DIM * 2;
    unsigned short* Wt = (unsigned short*)(ws + off); off += (size_t)9 * DIM * DIM * 2;
    int* cnt = (int*)(ws + off); off += (size_t)NBINS * 4;
    unsigned int* ebuf = (unsigned int*)(ws + off); off += (size_t)NBINS * BINCAP * 4;

    const int* src = edge_index;
    const int* dst = edge_index + N_EDGES;

    hipMemsetAsync(cnt, 0, (size_t)NBINS * 4, stream);
    prep_kernel<<<12500, 256, 0, stream>>>(x, relw, selfw, src, dst, edge_type,
                                           xb, Wt, cnt, ebuf);
    fused_kernel<<<N_PADROWS / 32, 256, 0, stream>>>(xb, Wt, cnt, ebuf, bias, out);
}

// Round 8
// 300.234 us; speedup vs baseline: 2.0694x; 1.1034x over previous
//
#include <hip/hip_runtime.h>

#define N_NODES 100000
#define DIM 128
#define N_REL 8
#define N_EDGES 625000
#define NG 6252              // dst 16-groups incl. pad (3126 blocks * 2)
#define NBINS (N_REL * NG)   // 50016 (rel, dst16-group) bins
#define BINCAP 64            // lambda = 12.5; P(bin > 64) ~ 1e-24 (passed r7)
#define N_PADROWS 100032

// fp32 -> bf16, round-to-nearest-even
__device__ __forceinline__ unsigned short f2bf(float f) {
    unsigned int u = __float_as_uint(f);
    u += 0x7fffu + ((u >> 16) & 1u);
    return (unsigned short)(u >> 16);
}

__device__ __forceinline__ float bf2f(unsigned short s) {
    return __uint_as_float(((unsigned int)s) << 16);
}

// prep (ONE pass): x->bf16 (12.8M elems, 4/thread), zero xb pad rows, W -> MFMA
// B-frag order, and bin every edge by (rel, dst>>4). Bin contents are UNORDERED;
// fused sorts each bin in-wave (ballot counting sort), so scan/fill/rank are gone.
__global__ __launch_bounds__(256) void prep_kernel(const float* __restrict__ x,
                                                   const float* __restrict__ relw,
                                                   const float* __restrict__ selfw,
                                                   const int* __restrict__ src,
                                                   const int* __restrict__ dst,
                                                   const int* __restrict__ rel,
                                                   unsigned short* __restrict__ xb,
                                                   unsigned short* __restrict__ Wt,
                                                   int* __restrict__ cnt,
                                                   unsigned int* __restrict__ ebuf) {
    int i = blockIdx.x * 256 + threadIdx.x;      // 0 .. 3,199,999 exact
    {
        float4 v = *(const float4*)(x + (size_t)i * 4);
        unsigned short t[4] = {f2bf(v.x), f2bf(v.y), f2bf(v.z), f2bf(v.w)};
        *(uint2*)(xb + (size_t)i * 4) = *(const uint2*)t;
    }
    if (i < 512) {  // zero pad rows 100000..100031
        uint4 z = {0, 0, 0, 0};
        *(uint4*)(xb + (size_t)N_NODES * DIM + i * 8) = z;
    }
    if (i < 147456) {  // Wt[(((r*4+ks)*8+t)*64+lane)*8+j] = W_r[din=ks*32+quad*8+j][dout=t*16+m16]
        int j = i & 7;
        int lane = (i >> 3) & 63;
        int t = (i >> 9) & 7;
        int ks = (i >> 12) & 3;
        int r = i >> 14;
        int m16 = lane & 15, quad = lane >> 4;
        int din = ks * 32 + quad * 8 + j;
        int dout = t * 16 + m16;
        float v = (r < 8) ? relw[(r << 14) + (din << 7) + dout] : selfw[(din << 7) + dout];
        Wt[i] = f2bf(v);
    }
    if (i < N_EDGES) {
        int d = dst[i];
        int bin = rel[i] * NG + (d >> 4);
        int pos = atomicAdd(&cnt[bin], 1);
        if (pos < BINCAP)
            ebuf[bin * BINCAP + pos] = (unsigned int)src[i] | ((unsigned int)(d & 15) << 17);
    }
}

typedef __attribute__((ext_vector_type(8))) short frag8;
typedef __attribute__((ext_vector_type(4))) float f32x4;

// In-wave counting sort of one bin's <=64 edge words by dst slot (bits 17..20).
// 16 ballots -> per-lane sorted position -> one ds_permute push. Inactive lanes
// (lane >= cl, garbage words) get positions cl..63 and are never consumed.
// ~110 VALU + 1 permute per bin; ~4 transient registers (the whole point: the
// register-hungry per-edge scatter of r7 is replaced by a per-bin sort, letting
// r3's proven 2-scalar run-detection gather run unchanged on sorted data).
__device__ __forceinline__ unsigned int sort_bin(unsigned int ew, int cl, int lane) {
    bool act = lane < cl;
    int mydl = act ? (int)((ew >> 17) & 15u) : 16;
    unsigned long long below = (1ull << lane) - 1ull;   // ok for lane 0..63
    int pos = 0;
#pragma unroll
    for (int j = 0; j < 16; j++) {
        unsigned long long mj = __ballot(mydl == j);
        int cj = (int)__popcll(mj);
        int rj = (int)__popcll(mj & below);
        pos += (mydl > j) ? cj : ((mydl == j) ? rj : 0);
    }
    unsigned long long inact = __ballot(!act);
    if (!act) pos = cl + (int)__popcll(inact & below);
    return (unsigned int)__builtin_amdgcn_ds_permute(pos << 2, (int)ew);
}

// Fused aggregate+transform (r3 gather core + binned input):
//  block = 32 dst rows, 4 waves: g=wave>>1 row-group (16 rows), h=wave&1 rel-group
//  (relations h*4..h*4+3; h=0 also does selfloop). Merge via LDS (2 barriers).
//  Per relation: bin (<=64 edges, 1 ew load, sorted up-front), run-detection mean
//  accumulation in 2 scalars (ax/ay), flush per dst run to swizzled 4KB tile,
//  A-frags from tile -> MFMA. 8-deep row-load batches, 1-ahead inside the bin,
//  next relation's first batch preloaded before MFMA (r3's pipeline, verbatim).
//  launch_bounds (256,4): cap 128 regs -- r1/r4/r7 all proved tighter caps spill.
__global__ __launch_bounds__(256, 4) void fused_kernel(const unsigned short* __restrict__ xb,
                                                       const unsigned short* __restrict__ Wt,
                                                       const int* __restrict__ cnt,
                                                       const unsigned int* __restrict__ ebuf,
                                                       const float* __restrict__ bias,
                                                       float* __restrict__ out) {
    __shared__ __align__(16) unsigned char ldsraw[4 * 4096];   // 16 KB

    const int tid = threadIdx.x;
    const int wave = tid >> 6, lane = tid & 63;
    const int g = wave >> 1, h = wave & 1;
    const int m16 = lane & 15, quad = lane >> 4;
    const int dbase = blockIdx.x * 32 + g * 16;
    const int grp = blockIdx.x * 2 + g;
    unsigned char* slab = ldsraw + wave * 4096;
    const unsigned int* xb32 = (const unsigned int*)xb;
    const int r0 = h * 4;

    // all 4 bin counts + contents up-front (8 independent loads, one latency)
    int clA = cnt[(r0 + 0) * NG + grp];
    int clB = cnt[(r0 + 1) * NG + grp];
    int clC = cnt[(r0 + 2) * NG + grp];
    int clD = cnt[(r0 + 3) * NG + grp];
    unsigned int ewA = ebuf[(size_t)((r0 + 0) * NG + grp) * BINCAP + lane];
    unsigned int ewB = ebuf[(size_t)((r0 + 1) * NG + grp) * BINCAP + lane];
    unsigned int ewC = ebuf[(size_t)((r0 + 2) * NG + grp) * BINCAP + lane];
    unsigned int ewD = ebuf[(size_t)((r0 + 3) * NG + grp) * BINCAP + lane];
    if (clA > BINCAP) clA = BINCAP;
    if (clB > BINCAP) clB = BINCAP;
    if (clC > BINCAP) clC = BINCAP;
    if (clD > BINCAP) clD = BINCAP;

    f32x4 acc[8];
#pragma unroll
    for (int t = 0; t < 8; t++) acc[t] = (f32x4){0.f, 0.f, 0.f, 0.f};

    if (h == 0) {
        // ---- selfloop: A-frags direct from xb (pad rows zeroed); hides bin loads ----
        const unsigned short* ap = xb + (size_t)(dbase + m16) * DIM;
#pragma unroll
        for (int ks = 0; ks < 4; ks++) {
            frag8 a = *(const frag8*)(ap + ks * 32 + quad * 8);
            const frag8* bp = (const frag8*)Wt + ((8 * 4 + ks) * 8) * 64 + lane;
#pragma unroll
            for (int t = 0; t < 8; t++)
                acc[t] = __builtin_amdgcn_mfma_f32_16x16x32_bf16(a, bp[t * 64], acc[t], 0, 0, 0);
        }
    }

    // sort all 4 bins up-front so the cross-relation preload pipeline works
    ewA = sort_bin(ewA, clA, lane);
    ewB = sort_bin(ewB, clB, lane);
    ewC = sort_bin(ewC, clC, lane);
    ewD = sort_bin(ewD, clD, lane);

    // preload first row-batch of relation 0
    unsigned int u0[8], v0[8];
    if (clA > 0) {
#pragma unroll
        for (int k = 0; k < 8; k++) {
            int li = k; if (li >= clA) li = clA - 1;
            u0[k] = (unsigned int)__builtin_amdgcn_readlane((int)ewA, li);
            v0[k] = xb32[(size_t)(u0[k] & 0x1ffffu) * 64 + lane];
        }
    }

#pragma unroll 1
    for (int r = 0; r < 4; r++) {
        // pre-zero the 4KB tile (empty segments stay zero)
        {
            uint4 z = {0, 0, 0, 0};
            *(uint4*)(slab + lane * 16) = z;
            *(uint4*)(slab + 1024 + lane * 16) = z;
            *(uint4*)(slab + 2048 + lane * 16) = z;
            *(uint4*)(slab + 3072 + lane * 16) = z;
        }

        if (clA > 0) {
            float ax = 0.f, ay = 0.f;
            int cur = -1, rn = 0;
#pragma unroll 1
            for (int i = 0; i < clA; i += 8) {
                // issue next batch while this one is processed
                unsigned int u1[8], v1[8];
                if (i + 8 < clA) {       // wave-uniform
#pragma unroll
                    for (int k = 0; k < 8; k++) {
                        int li = i + 8 + k; if (li >= clA) li = clA - 1;
                        u1[k] = (unsigned int)__builtin_amdgcn_readlane((int)ewA, li);
                        v1[k] = xb32[(size_t)(u1[k] & 0x1ffffu) * 64 + lane];
                    }
                }
                int kk = clA - i; if (kk > 8) kk = 8;
#pragma unroll
                for (int k = 0; k < 8; k++) {
                    if (k < kk) {                    // wave-uniform guard
                        int dl = (int)((u0[k] >> 17) & 15u);
                        if (dl != cur) {
                            if (rn > 0) {
                                float inv = __builtin_amdgcn_rcpf((float)rn);
                                unsigned int p = (unsigned int)f2bf(ax * inv) |
                                                 ((unsigned int)f2bf(ay * inv) << 16);
                                int bb = (lane >> 2) ^ cur;
                                *(unsigned int*)(slab + cur * 256 + bb * 16 + (lane & 3) * 4) = p;
                            }
                            cur = dl; ax = 0.f; ay = 0.f; rn = 0;
                        }
                        ax += bf2f((unsigned short)(v0[k] & 0xffffu));
                        ay += bf2f((unsigned short)(v0[k] >> 16));
                        rn++;
                    }
                }
                if (i + 8 < clA) {       // rotate (static indices only)
#pragma unroll
                    for (int k = 0; k < 8; k++) { u0[k] = u1[k]; v0[k] = v1[k]; }
                }
            }
            {   // final flush (rn>0 since clA>0)
                float inv = __builtin_amdgcn_rcpf((float)rn);
                unsigned int p = (unsigned int)f2bf(ax * inv) |
                                 ((unsigned int)f2bf(ay * inv) << 16);
                int bb = (lane >> 2) ^ cur;
                *(unsigned int*)(slab + cur * 256 + bb * 16 + (lane & 3) * 4) = p;
            }
        }

        // preload r+1's first row-batch NOW so its latency hides under the MFMA block
        if (r < 3 && clB > 0) {
#pragma unroll
            for (int k = 0; k < 8; k++) {
                int li = k; if (li >= clB) li = clB - 1;
                u0[k] = (unsigned int)__builtin_amdgcn_readlane((int)ewB, li);
                v0[k] = xb32[(size_t)(u0[k] & 0x1ffffu) * 64 + lane];
            }
        }

        // A-frags from swizzled tile + MFMA (LDS ops in-order per wave; no barrier)
#pragma unroll
        for (int ks = 0; ks < 4; ks++) {
            int bb = (4 * ks + quad) ^ m16;
            frag8 a = *(const frag8*)(slab + m16 * 256 + bb * 16);
            const frag8* bp = (const frag8*)Wt + (((r0 + r) * 4 + ks) * 8) * 64 + lane;
#pragma unroll
            for (int t = 0; t < 8; t++)
                acc[t] = __builtin_amdgcn_mfma_f32_16x16x32_bf16(a, bp[t * 64], acc[t], 0, 0, 0);
        }

        // rotate relation state (scalars only)
        clA = clB; clB = clC; clC = clD;
        ewA = ewB; ewB = ewC; ewC = ewD;
    }

    // ---- merge rel-halves: h=1 waves publish acc via LDS (reusing wave-pair slabs) ----
    __syncthreads();
    unsigned char* mbuf = ldsraw + g * 8192;
    if (h == 1) {
#pragma unroll
        for (int t = 0; t < 8; t++)
            *(f32x4*)(mbuf + (t * 64 + lane) * 16) = acc[t];
    }
    __syncthreads();
    if (h == 0) {
#pragma unroll
        for (int t = 0; t < 8; t++) {
            f32x4 m = *(f32x4*)(mbuf + (t * 64 + lane) * 16);
            acc[t] += m;
        }

        // ---- epilogue: +bias, two column-halves through mbuf (wave-private now;
        // own reads above are LDS-ordered before these writes)
        float* S = (float*)mbuf;
#pragma unroll
        for (int hh = 0; hh < 2; hh++) {
#pragma unroll
            for (int tt = 0; tt < 4; tt++) {
                int t = hh * 4 + tt;
                float bc = bias[t * 16 + m16];
#pragma unroll
                for (int i = 0; i < 4; i++)
                    S[(quad * 4 + i) * 68 + tt * 16 + m16] = acc[t][i] + bc;
            }
#pragma unroll
            for (int c = 0; c < 4; c++) {
                int row16 = c * 4 + quad;
                int gr = dbase + row16;
                if (gr < N_NODES)
                    *(float4*)(out + (size_t)gr * DIM + hh * 64 + m16 * 4) =
                        *(float4*)(S + row16 * 68 + m16 * 4);
            }
        }
    }
}

extern "C" void kernel_launch(void* const* d_in, const int* in_sizes, int n_in,
                              void* d_out, int out_size, void* d_ws, size_t ws_size,
                              hipStream_t stream) {
    const float* x = (const float*)d_in[0];
    const int* edge_index = (const int*)d_in[1]; // [2][E]: src then dst
    const int* edge_type = (const int*)d_in[2];
    const float* relw = (const float*)d_in[3];
    const float* selfw = (const float*)d_in[4];
    const float* bias = (const float*)d_in[5];
    float* out = (float*)d_out;
    (void)in_sizes; (void)n_in; (void)out_size; (void)ws_size;

    // ws: xb 25.6MB | Wt 0.29MB | cnt 0.2MB | ebuf 12.8MB  (~38.9MB total)
    char* ws = (char*)d_ws;
    size_t off = 0;
    unsigned short* xb = (unsigned short*)(ws + off); off += (size_t)N_PADROWS * DIM * 2;
    unsigned short* Wt = (unsigned short*)(ws + off); off += (size_t)9 * DIM * DIM * 2;
    int* cnt = (int*)(ws + off); off += (size_t)NBINS * 4;
    unsigned int* ebuf = (unsigned int*)(ws + off); off += (size_t)NBINS * BINCAP * 4;

    const int* src = edge_index;
    const int* dst = edge_index + N_EDGES;

    hipMemsetAsync(cnt, 0, (size_t)NBINS * 4, stream);
    prep_kernel<<<12500, 256, 0, stream>>>(x, relw, selfw, src, dst, edge_type,
                                           xb, Wt, cnt, ebuf);
    fused_kernel<<<N_PADROWS / 32, 256, 0, stream>>>(xb, Wt, cnt, ebuf, bias, out);
}

// Round 9
// 254.594 us; speedup vs baseline: 2.4404x; 1.1793x over previous
//
#include <hip/hip_runtime.h>

#define N_NODES 100000
#define DIM 128
#define N_REL 8
#define N_EDGES 625000
#define RN 800000            // N_REL * N_NODES (keys r*N+d)
#define N_PADROWS 100032     // 3126 blocks * 32 rows
#define SCAN_BLOCKS 98
#define SCAN_CHUNK 8192      // 256 threads * 32 elems

// fp32 -> bf16, round-to-nearest-even
__device__ __forceinline__ unsigned short f2bf(float f) {
    unsigned int u = __float_as_uint(f);
    u += 0x7fffu + ((u >> 16) & 1u);
    return (unsigned short)(u >> 16);
}

__device__ __forceinline__ float bf2f(unsigned short s) {
    return __uint_as_float(((unsigned int)s) << 16);
}

// prep: x->bf16 (12.8M elems, 4/thread, exact grid), zero xb pad rows,
// W -> MFMA B-frag order, (rel,dst) histogram + per-edge rank (degi pre-zeroed).
__global__ __launch_bounds__(256) void prep_kernel(const float* __restrict__ x,
                                                   const float* __restrict__ relw,
                                                   const float* __restrict__ selfw,
                                                   const int* __restrict__ dst,
                                                   const int* __restrict__ rel,
                                                   unsigned short* __restrict__ xb,
                                                   unsigned short* __restrict__ Wt,
                                                   int* __restrict__ degi,
                                                   int* __restrict__ rank) {
    int i = blockIdx.x * 256 + threadIdx.x;      // 0 .. 3,199,999 exact
    {
        float4 v = *(const float4*)(x + (size_t)i * 4);
        unsigned short t[4] = {f2bf(v.x), f2bf(v.y), f2bf(v.z), f2bf(v.w)};
        *(uint2*)(xb + (size_t)i * 4) = *(const uint2*)t;
    }
    if (i < 512) {  // zero pad rows 100000..100031
        uint4 z = {0, 0, 0, 0};
        *(uint4*)(xb + (size_t)N_NODES * DIM + i * 8) = z;
    }
    if (i < 147456) {  // Wt[(((r*4+ks)*8+t)*64+lane)*8+j] = W_r[din=ks*32+quad*8+j][dout=t*16+m16]
        int j = i & 7;
        int lane = (i >> 3) & 63;
        int t = (i >> 9) & 7;
        int ks = (i >> 12) & 3;
        int r = i >> 14;
        int m16 = lane & 15, quad = lane >> 4;
        int din = ks * 32 + quad * 8 + j;
        int dout = t * 16 + m16;
        float v = (r < 8) ? relw[(r << 14) + (din << 7) + dout] : selfw[(din << 7) + dout];
        Wt[i] = f2bf(v);
    }
    if (i < N_EDGES) {
        // rank within (rel,dst) segment; removes the atomic pass from fill_kernel
        rank[i] = atomicAdd(&degi[rel[i] * N_NODES + dst[i]], 1);
    }
}

// Single-pass exclusive scan of degi[RN] -> offs, wave-parallel lookback.
// 98 blocks are all co-resident (<< 256 CUs) so spinning on blockIdx order is safe.
// status word: bit31=prefix-ready, bit30=aggregate-ready, low 30 bits = value.
__global__ __launch_bounds__(256) void scan_kernel(const int* __restrict__ degi,
                                                   unsigned int* __restrict__ status,
                                                   int* __restrict__ offs) {
    __shared__ int lsum[256];
    __shared__ int lpfx;
    const int tid = threadIdx.x;
    const int b = blockIdx.x;
    const int base = b * SCAN_CHUNK + tid * 32;
    int v[32];
    int s = 0;
#pragma unroll
    for (int j = 0; j < 8; j++) {
        int idx = base + j * 4;
        int4 d = {0, 0, 0, 0};
        if (idx + 3 < RN) d = *(const int4*)(degi + idx);
        else {
            if (idx < RN) d.x = degi[idx];
            if (idx + 1 < RN) d.y = degi[idx + 1];
            if (idx + 2 < RN) d.z = degi[idx + 2];
        }
        v[j * 4] = d.x; v[j * 4 + 1] = d.y; v[j * 4 + 2] = d.z; v[j * 4 + 3] = d.w;
        s += d.x + d.y + d.z + d.w;
    }
    lsum[tid] = s;
    __syncthreads();
    for (int off = 1; off < 256; off <<= 1) {
        int p = (tid >= off) ? lsum[tid - off] : 0;
        __syncthreads();
        lsum[tid] += p;
        __syncthreads();
    }
    int thrbase = lsum[tid] - s;
    int total = lsum[255];

    if (b == 0) {
        if (tid == 0) {
            atomicExch(&status[0], 0x80000000u | (unsigned)total);
            lpfx = 0;
        }
    } else {
        if (tid == 0) atomicExch(&status[b], 0x40000000u | (unsigned)total);
        if (tid < 64) {
            int sum = 0;
            int j = b - 1;
            while (true) {
                int idx = j - tid;
                unsigned st = (idx >= 0) ? atomicAdd(&status[idx], 0u) : 0x80000000u;
                unsigned long long pball = __ballot(st & 0x80000000u);
                unsigned long long zball = __ballot(st == 0u);
                int fp = pball ? (__ffsll(pball) - 1) : 64;
                unsigned long long below = (fp >= 64) ? ~0ull : ((1ull << fp) - 1ull);
                if (zball & below) continue;         // gap not ready yet, re-read
                int lim = (fp < 64) ? fp : 63;
                int val = (tid <= lim) ? (int)(st & 0x3fffffffu) : 0;
                for (int o = 32; o > 0; o >>= 1) val += __shfl_down(val, o);
                sum += __shfl(val, 0);
                if (fp < 64) break;
                j -= 64;
            }
            if (tid == 0) {
                atomicExch(&status[b], 0x80000000u | (unsigned)(sum + total));
                lpfx = sum;
            }
        }
    }
    __syncthreads();
    int run = lpfx + thrbase;
#pragma unroll
    for (int j = 0; j < 32; j++) {
        int idx = base + j;
        if (idx < RN) {
            offs[idx] = run;
            if (idx == RN - 1) offs[RN] = run + v[j];
            run += v[j];
        }
    }
}

// Bin edges by key r*N+d using precomputed rank (no atomics).
// slot word = src | (d&15)<<17 (deg = segment length).
__global__ __launch_bounds__(256) void fill_kernel(const int* __restrict__ src,
                                                   const int* __restrict__ dst,
                                                   const int* __restrict__ rel,
                                                   const int* __restrict__ rank,
                                                   const int* __restrict__ offs,
                                                   unsigned int* __restrict__ ebuf) {
    int e = blockIdx.x * 256 + threadIdx.x;
    if (e < N_EDGES) {
        int d = dst[e];
        int key = rel[e] * N_NODES + d;
        int pos = offs[key] + rank[e];
        ebuf[pos] = (unsigned int)src[e] | ((unsigned int)(d & 15) << 17);
    }
}

typedef __attribute__((ext_vector_type(8))) short frag8;
typedef __attribute__((ext_vector_type(4))) float f32x4;

// Fused aggregate+transform == round-3's verified 105us kernel + two register-
// neutral edits:
//  (a) selfloop SPLIT across rel-halves (h=0: ks 0-1, h=1: ks 2-3; accs merge
//      at the end anyway) so BOTH waves hide their startup ew-load latency
//      under MFMA. r4 proved the idea sound; its regression was the (128,5)
//      spill (WRITE_SIZE +15MB), not this.
//  (b) s_setprio(1) around MFMA clusters: independent waves at mixed phases
//      (attn-like regime, m191 +4-7%), not GEMM lockstep (m190 null).
// Everything else r3-identical: block = 32 dst rows, 4 waves (g=row-group,
// h=rel-group), offs 2 rels ahead, edge words 1 rel ahead, first row-batch of
// r+1 issued before r's MFMA, 8-deep 1-ahead batches, 16KB LDS, (256,4).
__global__ __launch_bounds__(256, 4) void fused_kernel(const unsigned short* __restrict__ xb,
                                                       const unsigned short* __restrict__ Wt,
                                                       const int* __restrict__ offs2,
                                                       const unsigned int* __restrict__ ebuf,
                                                       const float* __restrict__ bias,
                                                       float* __restrict__ out) {
    __shared__ __align__(16) unsigned char ldsraw[16384];

    const int tid = threadIdx.x;
    const int wave = tid >> 6, lane = tid & 63;
    const int g = wave >> 1, h = wave & 1;
    const int m16 = lane & 15, quad = lane >> 4;
    const int dbase = blockIdx.x * 32 + g * 16;
    unsigned char* slab = ldsraw + wave * 4096;

    int cidx = dbase + lane;
    if (cidx > N_NODES) cidx = N_NODES;
    const int* obase = offs2 + (size_t)h * 4 * N_NODES + cidx;

    // descriptors for this wave's first two relations, issued up-front
    int obc = obase[0];
    int obn = obase[N_NODES];

    f32x4 acc[8];
#pragma unroll
    for (int t = 0; t < 8; t++) acc[t] = (f32x4){0.f, 0.f, 0.f, 0.f};

    // relation-0 state + edge-word prefetch (issue before selfloop so it arrives under it)
    int s0 = __builtin_amdgcn_readlane(obc, 0);
    int count = __builtin_amdgcn_readlane(obc, 16) - s0;
    unsigned int ewc = 0;
    if (lane < count) ewc = ebuf[s0 + lane];

    {   // ---- selfloop half (h=0: ks 0-1, h=1: ks 2-3): both waves get startup cover ----
        const unsigned short* ap = xb + (size_t)(dbase + m16) * DIM;
        __builtin_amdgcn_s_setprio(1);
#pragma unroll
        for (int k2 = 0; k2 < 2; k2++) {
            int ks = h * 2 + k2;
            frag8 a = *(const frag8*)(ap + ks * 32 + quad * 8);
            const frag8* bp = (const frag8*)Wt + ((8 * 4 + ks) * 8) * 64 + lane;
#pragma unroll
            for (int t = 0; t < 8; t++)
                acc[t] = __builtin_amdgcn_mfma_f32_16x16x32_bf16(a, bp[t * 64], acc[t], 0, 0, 0);
        }
        __builtin_amdgcn_s_setprio(0);
    }

    // preload first row-batch of relation 0
    unsigned int u0[8], v0[8];
    if (count > 0) {
        int cl = count; if (cl > 64) cl = 64;
#pragma unroll
        for (int k = 0; k < 8; k++) {
            int li = k; if (li >= cl) li = cl - 1;
            u0[k] = (unsigned int)__builtin_amdgcn_readlane((int)ewc, li);
            v0[k] = *((const unsigned int*)xb + (size_t)(u0[k] & 0x1ffffu) * 64 + lane);
        }
    }

#pragma unroll 1
    for (int r = 0; r < 4; r++) {
        // prefetch chain: r+1 edge words (offs already resident), r+2 offs
        int s0n = __builtin_amdgcn_readlane(obn, 0);
        int cntn = __builtin_amdgcn_readlane(obn, 16) - s0n;
        unsigned int ewn = 0;
        if (r < 3 && lane < cntn) ewn = ebuf[s0n + lane];
        int obn2 = (r < 2) ? obase[(r + 2) * N_NODES] : 0;

        // pre-zero the 4KB tile (empty segments stay zero)
        {
            uint4 z = {0, 0, 0, 0};
            *(uint4*)(slab + lane * 16) = z;
            *(uint4*)(slab + 1024 + lane * 16) = z;
            *(uint4*)(slab + 2048 + lane * 16) = z;
            *(uint4*)(slab + 3072 + lane * 16) = z;
        }

        if (count > 0) {
            float ax = 0.f, ay = 0.f;
            int cur = -1, cnt = 0;
#pragma unroll 1
            for (int b0 = 0; b0 < count; b0 += 64) {
                int cl = count - b0; if (cl > 64) cl = 64;
                unsigned int ew = ewc;
                if (b0 > 0) {            // rare (count>64): refill inline
                    ew = 0;
                    if (b0 + lane < count) ew = ebuf[s0 + b0 + lane];
#pragma unroll
                    for (int k = 0; k < 8; k++) {
                        int li = k; if (li >= cl) li = cl - 1;
                        u0[k] = (unsigned int)__builtin_amdgcn_readlane((int)ew, li);
                        v0[k] = *((const unsigned int*)xb + (size_t)(u0[k] & 0x1ffffu) * 64 + lane);
                    }
                }
#pragma unroll 1
                for (int i = 0; i < cl; i += 8) {
                    // issue next batch while this one is processed
                    unsigned int u1[8], v1[8];
                    if (i + 8 < cl) {    // wave-uniform
#pragma unroll
                        for (int k = 0; k < 8; k++) {
                            int li = i + 8 + k; if (li >= cl) li = cl - 1;
                            u1[k] = (unsigned int)__builtin_amdgcn_readlane((int)ew, li);
                            v1[k] = *((const unsigned int*)xb + (size_t)(u1[k] & 0x1ffffu) * 64 + lane);
                        }
                    }
                    int kk = cl - i; if (kk > 8) kk = 8;
#pragma unroll
                    for (int k = 0; k < 8; k++) {
                        if (k < kk) {                    // wave-uniform guard
                            int dl = (int)((u0[k] >> 17) & 15u);
                            if (dl != cur) {
                                if (cnt > 0) {
                                    float inv = __builtin_amdgcn_rcpf((float)cnt);
                                    unsigned int p = (unsigned int)f2bf(ax * inv) |
                                                     ((unsigned int)f2bf(ay * inv) << 16);
                                    int bb = (lane >> 2) ^ cur;
                                    *(unsigned int*)(slab + cur * 256 + bb * 16 + (lane & 3) * 4) = p;
                                }
                                cur = dl; ax = 0.f; ay = 0.f; cnt = 0;
                            }
                            ax += bf2f((unsigned short)(v0[k] & 0xffffu));
                            ay += bf2f((unsigned short)(v0[k] >> 16));
                            cnt++;
                        }
                    }
                    if (i + 8 < cl) {    // rotate (static indices only)
#pragma unroll
                        for (int k = 0; k < 8; k++) { u0[k] = u1[k]; v0[k] = v1[k]; }
                    }
                }
            }
            {   // final flush (cnt>0 since count>0)
                float inv = __builtin_amdgcn_rcpf((float)cnt);
                unsigned int p = (unsigned int)f2bf(ax * inv) |
                                 ((unsigned int)f2bf(ay * inv) << 16);
                int bb = (lane >> 2) ^ cur;
                *(unsigned int*)(slab + cur * 256 + bb * 16 + (lane & 3) * 4) = p;
            }
        }

        // preload r+1's first row-batch NOW so its latency hides under the MFMA block
        if (r < 3 && cntn > 0) {
            int cl = cntn; if (cl > 64) cl = 64;
#pragma unroll
            for (int k = 0; k < 8; k++) {
                int li = k; if (li >= cl) li = cl - 1;
                u0[k] = (unsigned int)__builtin_amdgcn_readlane((int)ewn, li);
                v0[k] = *((const unsigned int*)xb + (size_t)(u0[k] & 0x1ffffu) * 64 + lane);
            }
        }

        // A-frags from swizzled tile + MFMA (LDS ops in-order per wave; no barrier)
        __builtin_amdgcn_s_setprio(1);
#pragma unroll
        for (int ks = 0; ks < 4; ks++) {
            int bb = (4 * ks + quad) ^ m16;
            frag8 a = *(const frag8*)(slab + m16 * 256 + bb * 16);
            const frag8* bp = (const frag8*)Wt + (((h * 4 + r) * 4 + ks) * 8) * 64 + lane;
#pragma unroll
            for (int t = 0; t < 8; t++)
                acc[t] = __builtin_amdgcn_mfma_f32_16x16x32_bf16(a, bp[t * 64], acc[t], 0, 0, 0);
        }
        __builtin_amdgcn_s_setprio(0);

        // rotate relation state
        s0 = s0n; count = cntn; ewc = ewn; obn = obn2;
    }

    // ---- merge rel-halves: h=1 waves publish acc via LDS (reusing gather slabs) ----
    __syncthreads();
    unsigned char* mbuf = ldsraw + g * 8192;
    if (h == 1) {
#pragma unroll
        for (int t = 0; t < 8; t++)
            *(f32x4*)(mbuf + (t * 64 + lane) * 16) = acc[t];
    }
    __syncthreads();
    if (h == 0) {
#pragma unroll
        for (int t = 0; t < 8; t++) {
            f32x4 m = *(f32x4*)(mbuf + (t * 64 + lane) * 16);
            acc[t] += m;
        }

        // ---- epilogue: +bias, two column-halves through mbuf (wave-private now;
        // own reads above are LDS-ordered before these writes)
        float* S = (float*)mbuf;
#pragma unroll
        for (int hh = 0; hh < 2; hh++) {
#pragma unroll
            for (int tt = 0; tt < 4; tt++) {
                int t = hh * 4 + tt;
                float bc = bias[t * 16 + m16];
#pragma unroll
                for (int i = 0; i < 4; i++)
                    S[(quad * 4 + i) * 68 + tt * 16 + m16] = acc[t][i] + bc;
            }
#pragma unroll
            for (int c = 0; c < 4; c++) {
                int row16 = c * 4 + quad;
                int gr = dbase + row16;
                if (gr < N_NODES)
                    *(float4*)(out + (size_t)gr * DIM + hh * 64 + m16 * 4) =
                        *(float4*)(S + row16 * 68 + m16 * 4);
            }
        }
    }
}

extern "C" void kernel_launch(void* const* d_in, const int* in_sizes, int n_in,
                              void* d_out, int out_size, void* d_ws, size_t ws_size,
                              hipStream_t stream) {
    const float* x = (const float*)d_in[0];
    const int* edge_index = (const int*)d_in[1]; // [2][E]: src then dst
    const int* edge_type = (const int*)d_in[2];
    const float* relw = (const float*)d_in[3];
    const float* selfw = (const float*)d_in[4];
    const float* bias = (const float*)d_in[5];
    float* out = (float*)d_out;
    (void)in_sizes; (void)n_in; (void)out_size; (void)ws_size;

    // ws: xb 25.6MB | Wt 0.29MB | offs2 3.2MB | ebuf 2.5MB
    char* ws = (char*)d_ws;
    size_t off = 0;
    unsigned short* xb = (unsigned short*)(ws + off); off += (size_t)N_PADROWS * DIM * 2;
    unsigned short* Wt = (unsigned short*)(ws + off); off += (size_t)9 * DIM * DIM * 2;
    int* offs2 = (int*)(ws + off); off += (size_t)(RN + 4) * 4;
    unsigned int* ebuf = (unsigned int*)(ws + off); off += (size_t)N_EDGES * 4;

    // pre-fused scratch in d_out (fused_kernel overwrites all of out at the end):
    // degi[RN] | status[SCAN_BLOCKS+2] | rank[N_EDGES]  (total ~5.7MB << 51.2MB)
    int* degi = (int*)d_out;
    unsigned int* status = (unsigned int*)(degi + RN);
    int* rank = (int*)(status + SCAN_BLOCKS + 2);

    const int* src = edge_index;
    const int* dst = edge_index + N_EDGES;

    hipMemsetAsync(degi, 0, (size_t)RN * 4 + (SCAN_BLOCKS + 2) * 4, stream);
    prep_kernel<<<12500, 256, 0, stream>>>(x, relw, selfw, dst, edge_type, xb, Wt, degi, rank);
    scan_kernel<<<SCAN_BLOCKS, 256, 0, stream>>>(degi, status, offs2);
    fill_kernel<<<(N_EDGES + 255) / 256, 256, 0, stream>>>(src, dst, edge_type, rank, offs2, ebuf);
    fused_kernel<<<N_PADROWS / 32, 256, 0, stream>>>(xb, Wt, offs2, ebuf, bias, out);
}